// Round 16
// baseline (436.057 us; speedup 1.0000x reference)
//
#include <hip/hip_runtime.h>

#define BB     4
#define NQS    4096
#define NVS    9216
#define E_DIM  768
#define NHEAD  8
#define NPTS   4
#define HDIM   96
#define HFEAT  96
#define WFEAT  96
#define MQR    16384   // BB*NQS
#define NLNB   13312   // (MQ+MV)/4 ln blocks
#define NTRB   1152    // 24*24*2 transpose blocks
#define OROWS  64      // rows per fused msda+outproj block (128 KB LDS, 1/CU)

typedef __attribute__((ext_vector_type(8))) short  s8v;    // 8 x bf16 (4 VGPRs)
typedef __attribute__((ext_vector_type(4))) short  s4v;    // 4 x bf16
typedef __attribute__((ext_vector_type(4))) float  f4v;    // MFMA acc

__device__ __forceinline__ unsigned short f2bf(float x) {
    unsigned int u = __builtin_bit_cast(unsigned int, x);
    unsigned int r = (u + 0x7fffu + ((u >> 16) & 1u)) >> 16;
    return (unsigned short)r;
}
__device__ __forceinline__ float bf2f(unsigned short s) {
    unsigned int u = ((unsigned int)s) << 16;
    return __builtin_bit_cast(float, u);
}
__device__ __forceinline__ float bf2f_s(short s) {
    return bf2f((unsigned short)s);
}

#define GLD16(gp, lp) \
    __builtin_amdgcn_global_load_lds( \
        (__attribute__((address_space(1))) void*)(gp), \
        (__attribute__((address_space(3))) void*)(lp), 16, 0, 0)

// ---------------------------------------------------------------------------
// Fat prep kernel: ln_fused (blocks 0..13311) | weight transpose (next 1152)
// | wqc concat (last 384). 256 threads each; one launch instead of three.
// ---------------------------------------------------------------------------
__global__ __launch_bounds__(256) void prep_kernel(
    const float* __restrict__ q, const float* __restrict__ f,
    const float* __restrict__ qw, const float* __restrict__ qb,
    const float* __restrict__ fw, const float* __restrict__ fb,
    unsigned short* __restrict__ qout, unsigned short* __restrict__ fout,
    float* __restrict__ stats,
    const float* __restrict__ W0, const float* __restrict__ W1,
    unsigned short* __restrict__ T0, unsigned short* __restrict__ T1,
    const float* __restrict__ W_off, const float* __restrict__ W_attn,
    const float* __restrict__ b_off, const float* __restrict__ b_attn,
    unsigned short* __restrict__ Wqc, float* __restrict__ bcat) {
    __shared__ float tile[32][33];
    const int bid = blockIdx.x;

    if (bid < NLNB) {
        // ---- LayerNorm + bf16 cast: one wave per row, shuffle reduce ----
        const int wv = threadIdx.x >> 6, lane = threadIdx.x & 63;
        const int row = bid * 4 + wv;
        const bool isq = row < MQR;
        const float* x = isq ? (q + (size_t)row * E_DIM)
                             : (f + (size_t)(row - MQR) * E_DIM);
        const float4 v0 = ((const float4*)x)[lane];
        const float4 v1 = ((const float4*)x)[lane + 64];
        const float4 v2 = ((const float4*)x)[lane + 128];
        float s1 = v0.x + v0.y + v0.z + v0.w + v1.x + v1.y + v1.z + v1.w
                 + v2.x + v2.y + v2.z + v2.w;
        float s2 = v0.x * v0.x + v0.y * v0.y + v0.z * v0.z + v0.w * v0.w
                 + v1.x * v1.x + v1.y * v1.y + v1.z * v1.z + v1.w * v1.w
                 + v2.x * v2.x + v2.y * v2.y + v2.z * v2.z + v2.w * v2.w;
        #pragma unroll
        for (int o = 32; o > 0; o >>= 1) {
            s1 += __shfl_down(s1, o, 64);
            s2 += __shfl_down(s2, o, 64);
        }
        const float mean = __shfl(s1, 0, 64) * (1.0f / E_DIM);
        const float m2   = __shfl(s2, 0, 64) * (1.0f / E_DIM);
        const float rstd = rsqrtf(m2 - mean * mean + 1e-6f);
        if (isq && lane == 0) { stats[row * 2] = mean; stats[row * 2 + 1] = rstd; }
        const float* w = isq ? qw : fw;
        const float* b = isq ? qb : fb;
        unsigned short* o = isq ? (qout + (size_t)row * E_DIM)
                                : (fout + (size_t)(row - MQR) * E_DIM);
        const float4 vv[3] = {v0, v1, v2};
        #pragma unroll
        for (int c = 0; c < 3; c++) {
            const float4 w4 = ((const float4*)w)[lane + c * 64];
            const float4 b4 = ((const float4*)b)[lane + c * 64];
            s4v ov;
            ov[0] = (short)f2bf((vv[c].x - mean) * rstd * w4.x + b4.x);
            ov[1] = (short)f2bf((vv[c].y - mean) * rstd * w4.y + b4.y);
            ov[2] = (short)f2bf((vv[c].z - mean) * rstd * w4.z + b4.z);
            ov[3] = (short)f2bf((vv[c].w - mean) * rstd * w4.w + b4.w);
            ((s4v*)o)[lane + c * 64] = ov;
        }
    } else if (bid < NLNB + NTRB) {
        // ---- 32x32 transpose + bf16 cast of W_val / W_out ----
        const int idx = bid - NLNB;
        const int z = idx / 576, r2 = idx - z * 576;
        const float* W = z ? W1 : W0;
        unsigned short* Wt = z ? T1 : T0;
        const int bi = (r2 / 24) * 32, bj = (r2 % 24) * 32;
        const int t = threadIdx.x;
        const int r = t >> 5, c = t & 31;
        #pragma unroll
        for (int i = 0; i < 4; i++)
            tile[r + i * 8][c] = W[(size_t)(bi + r + i * 8) * E_DIM + bj + c];
        __syncthreads();
        #pragma unroll
        for (int i = 0; i < 4; i++)
            Wt[(size_t)(bj + r + i * 8) * E_DIM + bi + c] = f2bf(tile[c][r + i * 8]);
    } else {
        // ---- concat + transpose + zero-pad query-proj weights ----
        const int idx = (bid - NLNB - NTRB) * 256 + threadIdx.x;  // 128*768
        const int rrow = idx / E_DIM, k = idx % E_DIM;
        float v = 0.f;
        if (rrow < 64) v = W_off[(size_t)k * 64 + rrow];
        else if (rrow < 96) v = W_attn[(size_t)k * 32 + (rrow - 64)];
        Wqc[idx] = f2bf(v);
        if (idx < 128) {
            float b = 0.f;
            if (idx < 64) b = b_off[idx];
            else if (idx < 96) b = b_attn[idx - 64];
            bcat[idx] = b;
        }
    }
}

// ---------------------------------------------------------------------------
// 256x256 8-wave phase-pipelined NT-GEMM (r5/r9 measured-best schedule,
// value GEMM only — clean 432-block grid, no offsets tail).
// ---------------------------------------------------------------------------
template <int G>
__device__ __forceinline__ void tigroup(const unsigned short* as_, const s8v (&bfr)[2][4],
                                        f4v (&acc)[8][4], int quad, int l16, int wrow) {
    s8v af[2][2];
    #pragma unroll
    for (int c = 0; c < 2; c++)
        #pragma unroll
        for (int m = 0; m < 2; m++)
            af[c][m] = *(const s8v*)(as_ + ((size_t)((c * 4 + quad) * 256 + wrow * 128 + (G * 2 + m) * 16 + l16)) * 8);
    #pragma unroll
    for (int c = 0; c < 2; c++)
        #pragma unroll
        for (int m = 0; m < 2; m++)
            #pragma unroll
            for (int n = 0; n < 4; n++)
                acc[G * 2 + m][n] = __builtin_amdgcn_mfma_f32_16x16x32_bf16(
                    af[c][m], bfr[c][n], acc[G * 2 + m][n], 0, 0, 0);
}

__global__ __launch_bounds__(512, 2) void mfma_gemm256(
    const unsigned short* __restrict__ A, const unsigned short* __restrict__ Bt,
    const float* __restrict__ bias, unsigned short* __restrict__ C) {
    __shared__ unsigned short As[2][256 * 64];
    __shared__ unsigned short Bs[2][256 * 64];

    constexpr int K = E_DIM;
    constexpr int NT = K / 64;                 // 12 K-tiles
    const int tid = threadIdx.x;
    const int wave = tid >> 6;                 // 0..7
    const int lane = tid & 63;
    const int quad = lane >> 4;
    const int l16 = lane & 15;

    // XCD-aware bijective swizzle (nwg % 8 == 0: 432)
    const int nwg = gridDim.x * gridDim.y;
    const int flat = blockIdx.y * gridDim.x + blockIdx.x;
    const int cpx = nwg >> 3;
    const int swz = (flat & 7) * cpx + (flat >> 3);
    const int bx = swz % gridDim.x;
    const int by = swz / gridDim.x;
    const int bm = by * 256;
    const int bn = bx * 256;
    const int wrow = wave >> 2;                // 0..1
    const int wcol = wave & 3;                 // 0..3

    const unsigned short* gsrc[4][2];
    int ldst[4][2];
    #pragma unroll
    for (int h = 0; h < 4; h++) {
        #pragma unroll
        for (int i = 0; i < 2; i++) {
            const int ch = wave * 2 + i;
            const int s = ch >> 1, rsub = ch & 1;
            const int rw = (h & 1) * 128 + rsub * 64 + lane;   // row/col in [0,256)
            const unsigned short* base = (h < 2) ? (A + (size_t)(bm + rw) * K)
                                                 : (Bt + (size_t)(bn + rw) * K);
            gsrc[h][i] = base + s * 8;
            ldst[h][i] = (s * 256 + rw) * 8;
        }
    }

    #define STAGE256(h, kt, buf) do { \
        unsigned short* lb_ = ((h) < 2 ? &As[(buf)][0] : &Bs[(buf)][0]); \
        GLD16(gsrc[h][0] + (size_t)(kt) * 64, lb_ + ldst[h][0]); \
        GLD16(gsrc[h][1] + (size_t)(kt) * 64, lb_ + ldst[h][1]); \
    } while (0)

    f4v acc[8][4] = {};

    // prologue: tile 0 -> buf 0 (8 loads)
    #pragma unroll
    for (int h = 0; h < 4; h++) STAGE256(h, 0, 0);

    int cur = 0;
    for (int t = 0; t < NT; ++t) {
        const unsigned short* as_ = &As[cur][0];
        const unsigned short* bs_ = &Bs[cur][0];
        const int nb = cur ^ 1;
        const bool pf = (t + 1 < NT);

        // ---- phase 0: prefetch H0(t+1); wait prev tile landed (counted) ----
        if (pf) {
            STAGE256(0, t + 1, nb);
            asm volatile("s_waitcnt vmcnt(2)" ::: "memory");
        } else {
            asm volatile("s_waitcnt vmcnt(0)" ::: "memory");
        }
        __builtin_amdgcn_s_barrier();              // all waves' tile-t loads landed
        __builtin_amdgcn_sched_barrier(0);

        // read ALL B fragments once per tile into registers (8 x b128)
        s8v bfr[2][4];
        #pragma unroll
        for (int c = 0; c < 2; c++)
            #pragma unroll
            for (int n = 0; n < 4; n++)
                bfr[c][n] = *(const s8v*)(bs_ + ((size_t)((c * 4 + quad) * 256 + wcol * 64 + n * 16 + l16)) * 8);

        __builtin_amdgcn_s_setprio(1);
        tigroup<0>(as_, bfr, acc, quad, l16, wrow);
        __builtin_amdgcn_s_setprio(0);

        // ---- phase 1 ----
        if (pf) STAGE256(1, t + 1, nb);
        __builtin_amdgcn_s_setprio(1);
        tigroup<1>(as_, bfr, acc, quad, l16, wrow);
        __builtin_amdgcn_s_setprio(0);

        // ---- phase 2 ----
        if (pf) STAGE256(2, t + 1, nb);
        __builtin_amdgcn_s_setprio(1);
        tigroup<2>(as_, bfr, acc, quad, l16, wrow);
        __builtin_amdgcn_s_setprio(0);

        // ---- phase 3: A-reads, end-of-tile barrier, then MFMA ----
        if (pf) STAGE256(3, t + 1, nb);
        s8v af3[2][2];
        #pragma unroll
        for (int c = 0; c < 2; c++)
            #pragma unroll
            for (int m = 0; m < 2; m++)
                af3[c][m] = *(const s8v*)(as_ + ((size_t)((c * 4 + quad) * 256 + wrow * 128 + (6 + m) * 16 + l16)) * 8);
        asm volatile("s_waitcnt lgkmcnt(0)" ::: "memory");
        __builtin_amdgcn_sched_barrier(0);
        __builtin_amdgcn_s_barrier();              // all waves done reading buf cur
        __builtin_amdgcn_sched_barrier(0);
        __builtin_amdgcn_s_setprio(1);
        #pragma unroll
        for (int c = 0; c < 2; c++)
            #pragma unroll
            for (int m = 0; m < 2; m++)
                #pragma unroll
                for (int n = 0; n < 4; n++)
                    acc[6 + m][n] = __builtin_amdgcn_mfma_f32_16x16x32_bf16(
                        af3[c][m], bfr[c][n], acc[6 + m][n], 0, 0, 0);
        __builtin_amdgcn_s_setprio(0);

        cur ^= 1;
    }
    #undef STAGE256

    // ---- epilogue (r5 order: ti outer, tj, r inner) ----
    #pragma unroll
    for (int ti = 0; ti < 8; ti++) {
        const int gm_base = bm + wrow * 128 + ti * 16 + quad * 4;
        #pragma unroll
        for (int tj = 0; tj < 4; tj++) {
            const int gn = bn + wcol * 64 + tj * 16 + l16;
            const float bv = bias[gn];
            const int hh = gn / HDIM, dd = gn - hh * HDIM;
            #pragma unroll
            for (int r = 0; r < 4; r++) {
                const int gm = gm_base + r;
                const float v = acc[ti][tj][r] + bv;
                const int b = gm / NVS, s = gm - b * NVS;
                const size_t vidx = (((size_t)b * NHEAD + hh) * NVS + s) * HDIM + dd;
                C[vidx] = f2bf(v);
            }
        }
    }
}

// ---------------------------------------------------------------------------
// Fused OFFSETS-GEMM + MSDA + out-proj + final residual (r15 structure +
// offsets pre-phase). 256 blocks x 512 thr, 128 KB LDS (Ams 96K + off_s 32K),
// 1 block/CU, chunked XCD swizzle.
// Phase 0: offsets|attn = qbf[64 rows] @ Wqc^T (64x128, K=768). A/B fragments
//   DIRECT from global (qbf L3-resident, Wqc 192 KB L2 — r0-verified bcol
//   addressing); per-wave 16-col strip, 96 MFMA; result + bcat -> off_s LDS.
//   Replaces the gemm256 offsets tail AND the offattn HBM round trip.
// Phase 1: 6144 msda gather tasks, softmax inputs from off_s (LDS).
// Phase 2: 64x768 GEMM, A from swizzled LDS, B = Wo_t direct-global, fused
//   EPI2 residual epilogue.
// ---------------------------------------------------------------------------
__global__ __launch_bounds__(512, 2) void msda_oproj_kernel(
    const unsigned short* __restrict__ value,  // (B, 8, 9216, 96) bf16
    const unsigned short* __restrict__ qbf,    // (MQR, 768) bf16 LN(query)
    const unsigned short* __restrict__ Wqc,    // [128][768] bf16
    const float* __restrict__ bcat,            // [128]
    const float* __restrict__ refp,            // (MQR, 2)
    const unsigned short* __restrict__ Wo,     // Wo_t [n][k] 768x768 bf16
    const float* __restrict__ bias,            // b_out
    const float* __restrict__ query, const float* __restrict__ qstats,
    const float* __restrict__ lnw, const float* __restrict__ lnb,
    const float* __restrict__ gamma, float* __restrict__ out) {
    __shared__ unsigned short Ams[OROWS * E_DIM];   // 96 KB
    __shared__ float off_s[OROWS * 128];            // 32 KB

    // chunked XCD swizzle (grid 256, 256 % 8 == 0)
    const int bid = blockIdx.x;
    const int swzb = (bid & 7) * (256 >> 3) + (bid >> 3);
    const int row0 = swzb * OROWS;
    const int t = threadIdx.x;
    const int b = row0 >> 12;                  // uniform per block

    const int wave = t >> 6;                   // 0..7
    const int lane = t & 63;
    const int quad = lane >> 4;
    const int l16 = lane & 15;

    // ---------------- phase 0: offsets GEMM -> off_s ----------------
    {
        const unsigned short* arow[4];
        #pragma unroll
        for (int ti = 0; ti < 4; ti++)
            arow[ti] = qbf + (size_t)(row0 + ti * 16 + l16) * E_DIM + quad * 8;
        const unsigned short* brow = Wqc + (size_t)(wave * 16 + l16) * E_DIM + quad * 8;

        f4v a4[4] = {};
        #pragma unroll
        for (int k0 = 0; k0 < E_DIM; k0 += 32) {
            const s8v bf = *(const s8v*)(brow + k0);
            #pragma unroll
            for (int ti = 0; ti < 4; ti++) {
                const s8v af = *(const s8v*)(arow[ti] + k0);
                a4[ti] = __builtin_amdgcn_mfma_f32_16x16x32_bf16(af, bf, a4[ti], 0, 0, 0);
            }
        }
        const int col = wave * 16 + l16;
        const float bv = bcat[col];
        #pragma unroll
        for (int ti = 0; ti < 4; ti++)
            #pragma unroll
            for (int r = 0; r < 4; r++)
                off_s[(ti * 16 + quad * 4 + r) * 128 + col] = a4[ti][r] + bv;
    }
    __syncthreads();

    // ---------------- phase 1: msda -> LDS ----------------
    #pragma unroll
    for (int it = 0; it < 12; ++it) {
        const int tt = it * 512 + t;           // 0..6143
        const int r = tt / 96;
        const int rem = tt - r * 96;
        const int h = rem / 12;
        const int j = rem - h * 12;
        const int row = row0 + r;
        const float* oar = off_s + r * 128;
        float a0 = oar[64 + h * 4 + 0], a1 = oar[64 + h * 4 + 1];
        float a2 = oar[64 + h * 4 + 2], a3 = oar[64 + h * 4 + 3];
        float mx = fmaxf(fmaxf(a0, a1), fmaxf(a2, a3));
        float e0 = __expf(a0 - mx), e1 = __expf(a1 - mx);
        float e2 = __expf(a2 - mx), e3 = __expf(a3 - mx);
        float inv = 1.0f / (e0 + e1 + e2 + e3);
        const float aww[4] = {e0 * inv, e1 * inv, e2 * inv, e3 * inv};
        const float rx = refp[(size_t)row * 2 + 0] * WFEAT - 0.5f;
        const float ry = refp[(size_t)row * 2 + 1] * HFEAT - 0.5f;
        const unsigned short* vb = value + ((size_t)(b * NHEAD + h) * NVS) * HDIM + j * 8;

        float acc[8] = {};
        #pragma unroll
        for (int p = 0; p < 4; p++) {
            const float x = rx + oar[h * 8 + p * 2 + 0];
            const float y = ry + oar[h * 8 + p * 2 + 1];
            const float aw = aww[p];
            const float x0f = floorf(x), y0f = floorf(y);
            const float fx = x - x0f, fy = y - y0f;
            const int ix0 = (int)x0f, iy0 = (int)y0f;
            const int ix1 = ix0 + 1, iy1 = iy0 + 1;
            const float wx0 = (ix0 >= 0 && ix0 < WFEAT) ? (1.f - fx) : 0.f;
            const float wx1 = (ix1 >= 0 && ix1 < WFEAT) ? fx : 0.f;
            const float wy0 = (iy0 >= 0 && iy0 < HFEAT) ? (1.f - fy) : 0.f;
            const float wy1 = (iy1 >= 0 && iy1 < HFEAT) ? fy : 0.f;
            const int cx0 = min(max(ix0, 0), WFEAT - 1);
            const int cx1 = min(max(ix1, 0), WFEAT - 1);
            const int cy0 = min(max(iy0, 0), HFEAT - 1);
            const int cy1 = min(max(iy1, 0), HFEAT - 1);
            const float w00 = aw * wy0 * wx0, w01 = aw * wy0 * wx1;
            const float w10 = aw * wy1 * wx0, w11 = aw * wy1 * wx1;
            const s8v v00 = *(const s8v*)(vb + (size_t)(cy0 * WFEAT + cx0) * HDIM);
            const s8v v01 = *(const s8v*)(vb + (size_t)(cy0 * WFEAT + cx1) * HDIM);
            const s8v v10 = *(const s8v*)(vb + (size_t)(cy1 * WFEAT + cx0) * HDIM);
            const s8v v11 = *(const s8v*)(vb + (size_t)(cy1 * WFEAT + cx1) * HDIM);
            #pragma unroll
            for (int k = 0; k < 8; k++) {
                acc[k] += w00 * bf2f_s(v00[k]) + w01 * bf2f_s(v01[k])
                        + w10 * bf2f_s(v10[k]) + w11 * bf2f_s(v11[k]);
            }
        }
        s8v o;
        #pragma unroll
        for (int k = 0; k < 8; k++) o[k] = (short)f2bf(acc[k]);
        const int col16 = (h * 12 + j) ^ (r & 7);          // swizzled 16B slot
        *(s8v*)(&Ams[((size_t)r * 96 + col16) * 8]) = o;
    }
    __syncthreads();

    // ---------------- phase 2: 64x768 GEMM + residual ----------------
    const unsigned short* bcol[6];
    #pragma unroll
    for (int n = 0; n < 6; n++)
        bcol[n] = Wo + (size_t)(wave * 96 + n * 16 + l16) * E_DIM + quad * 8;

    f4v acc[4][6] = {};

    for (int k0 = 0; k0 < E_DIM; k0 += 32) {
        const int kc = (k0 >> 3) + quad;       // A col16 before swizzle
        s8v af[4], bf[6];
        #pragma unroll
        for (int m = 0; m < 4; m++) {
            const int r = m * 16 + l16;
            af[m] = *(const s8v*)(&Ams[((size_t)r * 96 + (kc ^ (r & 7))) * 8]);
        }
        #pragma unroll
        for (int n = 0; n < 6; n++)
            bf[n] = *(const s8v*)(bcol[n] + k0);
        #pragma unroll
        for (int m = 0; m < 4; m++)
            #pragma unroll
            for (int n = 0; n < 6; n++)
                acc[m][n] = __builtin_amdgcn_mfma_f32_16x16x32_bf16(af[m], bf[n], acc[m][n], 0, 0, 0);
    }

    #pragma unroll
    for (int m = 0; m < 4; m++) {
        const int gm_base = row0 + m * 16 + quad * 4;
        #pragma unroll
        for (int n = 0; n < 6; n++) {
            const int gn = wave * 96 + n * 16 + l16;
            const float bv = bias[gn];
            #pragma unroll
            for (int r = 0; r < 4; r++) {
                const int gm = gm_base + r;
                const size_t idx = (size_t)gm * E_DIM + gn;
                const float qv = query[idx];
                const float qln = (qv - qstats[gm * 2]) * qstats[gm * 2 + 1] * lnw[gn] + lnb[gn];
                out[idx] = qv + gamma[gn] * (qln + acc[m][n][r] + bv);
            }
        }
    }
}

// ---------------------------------------------------------------------------
extern "C" void kernel_launch(void* const* d_in, const int* in_sizes, int n_in,
                              void* d_out, int out_size, void* d_ws, size_t ws_size,
                              hipStream_t stream) {
    (void)in_sizes; (void)n_in; (void)out_size; (void)ws_size;

    const float* query  = (const float*)d_in[0];
    const float* refp   = (const float*)d_in[1];
    const float* feat   = (const float*)d_in[2];
    const float* ln_q_w = (const float*)d_in[5];
    const float* ln_q_b = (const float*)d_in[6];
    const float* ln_f_w = (const float*)d_in[7];
    const float* ln_f_b = (const float*)d_in[8];
    const float* W_val  = (const float*)d_in[9];
    const float* b_val  = (const float*)d_in[10];
    const float* W_off  = (const float*)d_in[11];
    const float* b_off  = (const float*)d_in[12];
    const float* W_attn = (const float*)d_in[13];
    const float* b_attn = (const float*)d_in[14];
    const float* W_out  = (const float*)d_in[15];
    const float* b_out  = (const float*)d_in[16];
    const float* gamma  = (const float*)d_in[17];
    float* out = (float*)d_out;

    const int MQ = BB * NQS;   // 16384
    const int MV = BB * NVS;   // 36864

    // Workspace layout (bytes)
    char* ws = (char*)d_ws;
    float*          q_stats = (float*)(ws + 0);                   //     131,072
    unsigned short* qbf     = (unsigned short*)(ws + 131072);     //  25,165,824
    unsigned short* fbf     = (unsigned short*)(ws + 25296896);   //  56,623,104
    unsigned short* val_bf  = (unsigned short*)(ws + 81920000);   //  56,623,104 (B,H,S,D)
    unsigned short* Wv_t    = (unsigned short*)(ws + 172097536);  //   1,179,648
    unsigned short* Wo_t    = (unsigned short*)(ws + 173277184);  //   1,179,648
    unsigned short* Wqc_t   = (unsigned short*)(ws + 174456832);  //     196,608
    float*          bcat    = (float*)(ws + 174653440);           //         512

    // 1. prep: LN (query+feat) + both weight transposes + wqc concat
    prep_kernel<<<NLNB + NTRB + 384, 256, 0, stream>>>(
        query, feat, ln_q_w, ln_q_b, ln_f_w, ln_f_b, qbf, fbf, q_stats,
        W_val, W_out, Wv_t, Wo_t, W_off, W_attn, b_off, b_attn, Wqc_t, bcat);

    // 2. value = LN(feat) @ W_value + b_value -> bf16, (B,H,S,D) layout
    mfma_gemm256<<<dim3(E_DIM / 256, MV / 256), 512, 0, stream>>>(
        fbf, Wv_t, b_val, val_bf);

    // 3. fused offsets-GEMM + msda + out-proj + residual (256 blocks, 1/CU)
    msda_oproj_kernel<<<MQ / OROWS, 512, 0, stream>>>(
        val_bf, qbf, Wqc_t, bcat, refp, Wo_t, b_out, query, q_stats,
        ln_q_w, ln_q_b, gamma, out);
}

// Round 17
// 410.612 us; speedup vs baseline: 1.0620x; 1.0620x over previous
//
#include <hip/hip_runtime.h>

#define BB     4
#define NQS    4096
#define NVS    9216
#define E_DIM  768
#define NHEAD  8
#define NPTS   4
#define HDIM   96
#define HFEAT  96
#define WFEAT  96
#define MQR    16384   // BB*NQS
#define NLNB   13312   // (MQ+MV)/4 ln blocks
#define NTRB   1152    // 24*24*2 transpose blocks
#define NVALB  432     // value-gemm blocks (3 x 144)
#define OROWS  64      // rows per fused msda+outproj block (96 KB LDS, 1/CU)

typedef __attribute__((ext_vector_type(8))) short  s8v;    // 8 x bf16 (4 VGPRs)
typedef __attribute__((ext_vector_type(4))) short  s4v;    // 4 x bf16
typedef __attribute__((ext_vector_type(4))) float  f4v;    // MFMA acc

__device__ __forceinline__ unsigned short f2bf(float x) {
    unsigned int u = __builtin_bit_cast(unsigned int, x);
    unsigned int r = (u + 0x7fffu + ((u >> 16) & 1u)) >> 16;
    return (unsigned short)r;
}
__device__ __forceinline__ float bf2f(unsigned short s) {
    unsigned int u = ((unsigned int)s) << 16;
    return __builtin_bit_cast(float, u);
}
__device__ __forceinline__ float bf2f_s(short s) {
    return bf2f((unsigned short)s);
}

#define GLD16(gp, lp) \
    __builtin_amdgcn_global_load_lds( \
        (__attribute__((address_space(1))) void*)(gp), \
        (__attribute__((address_space(3))) void*)(lp), 16, 0, 0)

// ---------------------------------------------------------------------------
// Fat prep kernel: ln_fused (blocks 0..13311) | weight transpose (next 1152)
// | wqc concat (last 384). 256 threads each; one launch instead of three.
// ---------------------------------------------------------------------------
__global__ __launch_bounds__(256) void prep_kernel(
    const float* __restrict__ q, const float* __restrict__ f,
    const float* __restrict__ qw, const float* __restrict__ qb,
    const float* __restrict__ fw, const float* __restrict__ fb,
    unsigned short* __restrict__ qout, unsigned short* __restrict__ fout,
    float* __restrict__ stats,
    const float* __restrict__ W0, const float* __restrict__ W1,
    unsigned short* __restrict__ T0, unsigned short* __restrict__ T1,
    const float* __restrict__ W_off, const float* __restrict__ W_attn,
    const float* __restrict__ b_off, const float* __restrict__ b_attn,
    unsigned short* __restrict__ Wqc, float* __restrict__ bcat) {
    __shared__ float tile[32][33];
    const int bid = blockIdx.x;

    if (bid < NLNB) {
        // ---- LayerNorm + bf16 cast: one wave per row, shuffle reduce ----
        const int wv = threadIdx.x >> 6, lane = threadIdx.x & 63;
        const int row = bid * 4 + wv;
        const bool isq = row < MQR;
        const float* x = isq ? (q + (size_t)row * E_DIM)
                             : (f + (size_t)(row - MQR) * E_DIM);
        const float4 v0 = ((const float4*)x)[lane];
        const float4 v1 = ((const float4*)x)[lane + 64];
        const float4 v2 = ((const float4*)x)[lane + 128];
        float s1 = v0.x + v0.y + v0.z + v0.w + v1.x + v1.y + v1.z + v1.w
                 + v2.x + v2.y + v2.z + v2.w;
        float s2 = v0.x * v0.x + v0.y * v0.y + v0.z * v0.z + v0.w * v0.w
                 + v1.x * v1.x + v1.y * v1.y + v1.z * v1.z + v1.w * v1.w
                 + v2.x * v2.x + v2.y * v2.y + v2.z * v2.z + v2.w * v2.w;
        #pragma unroll
        for (int o = 32; o > 0; o >>= 1) {
            s1 += __shfl_down(s1, o, 64);
            s2 += __shfl_down(s2, o, 64);
        }
        const float mean = __shfl(s1, 0, 64) * (1.0f / E_DIM);
        const float m2   = __shfl(s2, 0, 64) * (1.0f / E_DIM);
        const float rstd = rsqrtf(m2 - mean * mean + 1e-6f);
        if (isq && lane == 0) { stats[row * 2] = mean; stats[row * 2 + 1] = rstd; }
        const float* w = isq ? qw : fw;
        const float* b = isq ? qb : fb;
        unsigned short* o = isq ? (qout + (size_t)row * E_DIM)
                                : (fout + (size_t)(row - MQR) * E_DIM);
        const float4 vv[3] = {v0, v1, v2};
        #pragma unroll
        for (int c = 0; c < 3; c++) {
            const float4 w4 = ((const float4*)w)[lane + c * 64];
            const float4 b4 = ((const float4*)b)[lane + c * 64];
            s4v ov;
            ov[0] = (short)f2bf((vv[c].x - mean) * rstd * w4.x + b4.x);
            ov[1] = (short)f2bf((vv[c].y - mean) * rstd * w4.y + b4.y);
            ov[2] = (short)f2bf((vv[c].z - mean) * rstd * w4.z + b4.z);
            ov[3] = (short)f2bf((vv[c].w - mean) * rstd * w4.w + b4.w);
            ((s4v*)o)[lane + c * 64] = ov;
        }
    } else if (bid < NLNB + NTRB) {
        // ---- 32x32 transpose + bf16 cast of W_val / W_out ----
        const int idx = bid - NLNB;
        const int z = idx / 576, r2 = idx - z * 576;
        const float* W = z ? W1 : W0;
        unsigned short* Wt = z ? T1 : T0;
        const int bi = (r2 / 24) * 32, bj = (r2 % 24) * 32;
        const int t = threadIdx.x;
        const int r = t >> 5, c = t & 31;
        #pragma unroll
        for (int i = 0; i < 4; i++)
            tile[r + i * 8][c] = W[(size_t)(bi + r + i * 8) * E_DIM + bj + c];
        __syncthreads();
        #pragma unroll
        for (int i = 0; i < 4; i++)
            Wt[(size_t)(bj + r + i * 8) * E_DIM + bi + c] = f2bf(tile[c][r + i * 8]);
    } else {
        // ---- concat + transpose + zero-pad query-proj weights ----
        const int idx = (bid - NLNB - NTRB) * 256 + threadIdx.x;  // 128*768
        const int rrow = idx / E_DIM, k = idx % E_DIM;
        float v = 0.f;
        if (rrow < 64) v = W_off[(size_t)k * 64 + rrow];
        else if (rrow < 96) v = W_attn[(size_t)k * 32 + (rrow - 64)];
        Wqc[idx] = f2bf(v);
        if (idx < 128) {
            float b = 0.f;
            if (idx < 64) b = b_off[idx];
            else if (idx < 96) b = b_attn[idx - 64];
            bcat[idx] = b;
        }
    }
}

// ---------------------------------------------------------------------------
// Fat main GEMM (r12/r15, measured best): blocks 0..431 = value 256x256
// (r5/r9 schedule); blocks 432..559 = offsets 128x128 GEMM in the tail.
// ---------------------------------------------------------------------------
template <int G>
__device__ __forceinline__ void tigroup(const unsigned short* as_, const s8v (&bfr)[2][4],
                                        f4v (&acc)[8][4], int quad, int l16, int wrow) {
    s8v af[2][2];
    #pragma unroll
    for (int c = 0; c < 2; c++)
        #pragma unroll
        for (int m = 0; m < 2; m++)
            af[c][m] = *(const s8v*)(as_ + ((size_t)((c * 4 + quad) * 256 + wrow * 128 + (G * 2 + m) * 16 + l16)) * 8);
    #pragma unroll
    for (int c = 0; c < 2; c++)
        #pragma unroll
        for (int m = 0; m < 2; m++)
            #pragma unroll
            for (int n = 0; n < 4; n++)
                acc[G * 2 + m][n] = __builtin_amdgcn_mfma_f32_16x16x32_bf16(
                    af[c][m], bfr[c][n], acc[G * 2 + m][n], 0, 0, 0);
}

__global__ __launch_bounds__(512, 2) void mfma_gemm256(
    const unsigned short* __restrict__ A, const unsigned short* __restrict__ Bt,
    const float* __restrict__ bias, unsigned short* __restrict__ C,
    const unsigned short* __restrict__ Aq, const unsigned short* __restrict__ Wqc,
    const float* __restrict__ bcat, float* __restrict__ offattn) {
    __shared__ unsigned short As[2][256 * 64];
    __shared__ unsigned short Bs[2][256 * 64];

    constexpr int K = E_DIM;
    constexpr int NT = K / 64;                 // 12 K-tiles
    const int tid = threadIdx.x;
    const int wave = tid >> 6;                 // 0..7
    const int lane = tid & 63;
    const int quad = lane >> 4;
    const int l16 = lane & 15;

    if (blockIdx.x < NVALB) {
        // =================== value path (r5/r9 schedule, verbatim) ==========
        const int flat = blockIdx.x;
        const int cpx = NVALB >> 3;
        const int swz = (flat & 7) * cpx + (flat >> 3);
        const int bx = swz % 3;
        const int by = swz / 3;
        const int bm = by * 256;
        const int bn = bx * 256;
        const int wrow = wave >> 2;                // 0..1
        const int wcol = wave & 3;                 // 0..3

        const unsigned short* gsrc[4][2];
        int ldst[4][2];
        #pragma unroll
        for (int h = 0; h < 4; h++) {
            #pragma unroll
            for (int i = 0; i < 2; i++) {
                const int ch = wave * 2 + i;
                const int s = ch >> 1, rsub = ch & 1;
                const int rw = (h & 1) * 128 + rsub * 64 + lane;   // [0,256)
                const unsigned short* base = (h < 2) ? (A + (size_t)(bm + rw) * K)
                                                     : (Bt + (size_t)(bn + rw) * K);
                gsrc[h][i] = base + s * 8;
                ldst[h][i] = (s * 256 + rw) * 8;
            }
        }

        #define STAGE256(h, kt, buf) do { \
            unsigned short* lb_ = ((h) < 2 ? &As[(buf)][0] : &Bs[(buf)][0]); \
            GLD16(gsrc[h][0] + (size_t)(kt) * 64, lb_ + ldst[h][0]); \
            GLD16(gsrc[h][1] + (size_t)(kt) * 64, lb_ + ldst[h][1]); \
        } while (0)

        f4v acc[8][4] = {};

        #pragma unroll
        for (int h = 0; h < 4; h++) STAGE256(h, 0, 0);

        int cur = 0;
        for (int t = 0; t < NT; ++t) {
            const unsigned short* as_ = &As[cur][0];
            const unsigned short* bs_ = &Bs[cur][0];
            const int nb = cur ^ 1;
            const bool pf = (t + 1 < NT);

            if (pf) {
                STAGE256(0, t + 1, nb);
                asm volatile("s_waitcnt vmcnt(2)" ::: "memory");
            } else {
                asm volatile("s_waitcnt vmcnt(0)" ::: "memory");
            }
            __builtin_amdgcn_s_barrier();
            __builtin_amdgcn_sched_barrier(0);

            s8v bfr[2][4];
            #pragma unroll
            for (int c = 0; c < 2; c++)
                #pragma unroll
                for (int n = 0; n < 4; n++)
                    bfr[c][n] = *(const s8v*)(bs_ + ((size_t)((c * 4 + quad) * 256 + wcol * 64 + n * 16 + l16)) * 8);

            __builtin_amdgcn_s_setprio(1);
            tigroup<0>(as_, bfr, acc, quad, l16, wrow);
            __builtin_amdgcn_s_setprio(0);

            if (pf) STAGE256(1, t + 1, nb);
            __builtin_amdgcn_s_setprio(1);
            tigroup<1>(as_, bfr, acc, quad, l16, wrow);
            __builtin_amdgcn_s_setprio(0);

            if (pf) STAGE256(2, t + 1, nb);
            __builtin_amdgcn_s_setprio(1);
            tigroup<2>(as_, bfr, acc, quad, l16, wrow);
            __builtin_amdgcn_s_setprio(0);

            if (pf) STAGE256(3, t + 1, nb);
            s8v af3[2][2];
            #pragma unroll
            for (int c = 0; c < 2; c++)
                #pragma unroll
                for (int m = 0; m < 2; m++)
                    af3[c][m] = *(const s8v*)(as_ + ((size_t)((c * 4 + quad) * 256 + wrow * 128 + (6 + m) * 16 + l16)) * 8);
            asm volatile("s_waitcnt lgkmcnt(0)" ::: "memory");
            __builtin_amdgcn_sched_barrier(0);
            __builtin_amdgcn_s_barrier();
            __builtin_amdgcn_sched_barrier(0);
            __builtin_amdgcn_s_setprio(1);
            #pragma unroll
            for (int c = 0; c < 2; c++)
                #pragma unroll
                for (int m = 0; m < 2; m++)
                    #pragma unroll
                    for (int n = 0; n < 4; n++)
                        acc[6 + m][n] = __builtin_amdgcn_mfma_f32_16x16x32_bf16(
                            af3[c][m], bfr[c][n], acc[6 + m][n], 0, 0, 0);
            __builtin_amdgcn_s_setprio(0);

            cur ^= 1;
        }
        #undef STAGE256

        #pragma unroll
        for (int ti = 0; ti < 8; ti++) {
            const int gm_base = bm + wrow * 128 + ti * 16 + quad * 4;
            #pragma unroll
            for (int tj = 0; tj < 4; tj++) {
                const int gn = bn + wcol * 64 + tj * 16 + l16;
                const float bv = bias[gn];
                const int hh = gn / HDIM, dd = gn - hh * HDIM;
                #pragma unroll
                for (int r = 0; r < 4; r++) {
                    const int gm = gm_base + r;
                    const float v = acc[ti][tj][r] + bv;
                    const int b = gm / NVS, s = gm - b * NVS;
                    const size_t vidx = (((size_t)b * NHEAD + hh) * NVS + s) * HDIM + dd;
                    C[vidx] = f2bf(v);
                }
            }
        }
    } else {
        // ============== offsets path: 128x128, 8 waves, single-buffered =====
        const int bm = (blockIdx.x - NVALB) * 128;
        const int wrow = wave >> 2;                // 0..1 (64-row halves)
        const int wcol = wave & 3;                 // 0..3 (32-col quarters)
        unsigned short* As0 = &As[0][0];           // reuse 16 KB of value LDS
        unsigned short* Bs0 = &Bs[0][0];

        const unsigned short* arow[2];
        const unsigned short* brow[2];
        int loff[2];
        #pragma unroll
        for (int i = 0; i < 2; i++) {
            const int ch = wave * 2 + i;           // 0..15
            const int s = ch >> 1, r = (ch & 1) * 64 + lane;   // kseg, row
            arow[i] = Aq + (size_t)(bm + r) * K + s * 8;
            brow[i] = Wqc + (size_t)r * K + s * 8;             // 128 rows total
            loff[i] = (s * 128 + r) * 8;
        }

        f4v accq[4][2] = {};

        for (int k0 = 0; k0 < K; k0 += 64) {
            #pragma unroll
            for (int i = 0; i < 2; i++) GLD16(arow[i] + k0, As0 + loff[i]);
            #pragma unroll
            for (int i = 0; i < 2; i++) GLD16(brow[i] + k0, Bs0 + loff[i]);

            __syncthreads();

            #pragma unroll
            for (int c = 0; c < 2; c++) {
                s8v af[4], bf[2];
                #pragma unroll
                for (int m = 0; m < 4; m++)
                    af[m] = *(const s8v*)(As0 + ((size_t)((c * 4 + quad) * 128 + wrow * 64 + m * 16 + l16)) * 8);
                #pragma unroll
                for (int n = 0; n < 2; n++)
                    bf[n] = *(const s8v*)(Bs0 + ((size_t)((c * 4 + quad) * 128 + wcol * 32 + n * 16 + l16)) * 8);
                #pragma unroll
                for (int m = 0; m < 4; m++)
                    #pragma unroll
                    for (int n = 0; n < 2; n++)
                        accq[m][n] = __builtin_amdgcn_mfma_f32_16x16x32_bf16(af[m], bf[n], accq[m][n], 0, 0, 0);
            }
            __syncthreads();
        }

        #pragma unroll
        for (int m = 0; m < 4; m++) {
            const int gm_base = bm + wrow * 64 + m * 16 + quad * 4;
            #pragma unroll
            for (int n = 0; n < 2; n++) {
                const int gn = wcol * 32 + n * 16 + l16;
                const float bv = bcat[gn];
                #pragma unroll
                for (int r = 0; r < 4; r++)
                    offattn[(size_t)(gm_base + r) * 128 + gn] = accq[m][n][r] + bv;
            }
        }
    }
}

// ---------------------------------------------------------------------------
// Fused MSDA + out-proj + final residual (r15, measured best: OROWS=64,
// 1/CU, chunked XCD swizzle so batch b's blocks co-locate on 2 XCDs).
// ---------------------------------------------------------------------------
__global__ __launch_bounds__(512, 2) void msda_oproj_kernel(
    const unsigned short* __restrict__ value,  // (B, 8, 9216, 96) bf16
    const float* __restrict__ oa,              // (MQR, 128): 0-63 off, 64-95 attn
    const float* __restrict__ refp,            // (MQR, 2)
    const unsigned short* __restrict__ Wo,     // Wo_t [n][k] 768x768 bf16
    const float* __restrict__ bias,            // b_out
    const float* __restrict__ query, const float* __restrict__ qstats,
    const float* __restrict__ lnw, const float* __restrict__ lnb,
    const float* __restrict__ gamma, float* __restrict__ out) {
    __shared__ unsigned short Ams[OROWS * E_DIM];   // 96 KB

    // chunked XCD swizzle (grid 256, 256 % 8 == 0)
    const int bid = blockIdx.x;
    const int swzb = (bid & 7) * (256 >> 3) + (bid >> 3);
    const int row0 = swzb * OROWS;
    const int t = threadIdx.x;
    const int b = row0 >> 12;                  // uniform per block

    // ---------------- phase 1: msda -> LDS ----------------
    #pragma unroll
    for (int it = 0; it < 12; ++it) {
        const int tt = it * 512 + t;           // 0..6143
        const int r = tt / 96;
        const int rem = tt - r * 96;
        const int h = rem / 12;
        const int j = rem - h * 12;
        const int row = row0 + r;
        const float* oar = oa + (size_t)row * 128;
        float a0 = oar[64 + h * 4 + 0], a1 = oar[64 + h * 4 + 1];
        float a2 = oar[64 + h * 4 + 2], a3 = oar[64 + h * 4 + 3];
        float mx = fmaxf(fmaxf(a0, a1), fmaxf(a2, a3));
        float e0 = __expf(a0 - mx), e1 = __expf(a1 - mx);
        float e2 = __expf(a2 - mx), e3 = __expf(a3 - mx);
        float inv = 1.0f / (e0 + e1 + e2 + e3);
        const float aww[4] = {e0 * inv, e1 * inv, e2 * inv, e3 * inv};
        const float rx = refp[(size_t)row * 2 + 0] * WFEAT - 0.5f;
        const float ry = refp[(size_t)row * 2 + 1] * HFEAT - 0.5f;
        const unsigned short* vb = value + ((size_t)(b * NHEAD + h) * NVS) * HDIM + j * 8;

        float acc[8] = {};
        #pragma unroll
        for (int p = 0; p < 4; p++) {
            const float x = rx + oar[h * 8 + p * 2 + 0];
            const float y = ry + oar[h * 8 + p * 2 + 1];
            const float aw = aww[p];
            const float x0f = floorf(x), y0f = floorf(y);
            const float fx = x - x0f, fy = y - y0f;
            const int ix0 = (int)x0f, iy0 = (int)y0f;
            const int ix1 = ix0 + 1, iy1 = iy0 + 1;
            const float wx0 = (ix0 >= 0 && ix0 < WFEAT) ? (1.f - fx) : 0.f;
            const float wx1 = (ix1 >= 0 && ix1 < WFEAT) ? fx : 0.f;
            const float wy0 = (iy0 >= 0 && iy0 < HFEAT) ? (1.f - fy) : 0.f;
            const float wy1 = (iy1 >= 0 && iy1 < HFEAT) ? fy : 0.f;
            const int cx0 = min(max(ix0, 0), WFEAT - 1);
            const int cx1 = min(max(ix1, 0), WFEAT - 1);
            const int cy0 = min(max(iy0, 0), HFEAT - 1);
            const int cy1 = min(max(iy1, 0), HFEAT - 1);
            const float w00 = aw * wy0 * wx0, w01 = aw * wy0 * wx1;
            const float w10 = aw * wy1 * wx0, w11 = aw * wy1 * wx1;
            const s8v v00 = *(const s8v*)(vb + (size_t)(cy0 * WFEAT + cx0) * HDIM);
            const s8v v01 = *(const s8v*)(vb + (size_t)(cy0 * WFEAT + cx1) * HDIM);
            const s8v v10 = *(const s8v*)(vb + (size_t)(cy1 * WFEAT + cx0) * HDIM);
            const s8v v11 = *(const s8v*)(vb + (size_t)(cy1 * WFEAT + cx1) * HDIM);
            #pragma unroll
            for (int k = 0; k < 8; k++) {
                acc[k] += w00 * bf2f_s(v00[k]) + w01 * bf2f_s(v01[k])
                        + w10 * bf2f_s(v10[k]) + w11 * bf2f_s(v11[k]);
            }
        }
        s8v o;
        #pragma unroll
        for (int k = 0; k < 8; k++) o[k] = (short)f2bf(acc[k]);
        const int col16 = (h * 12 + j) ^ (r & 7);          // swizzled 16B slot
        *(s8v*)(&Ams[((size_t)r * 96 + col16) * 8]) = o;
    }
    __syncthreads();

    // ---------------- phase 2: 64x768 GEMM + residual ----------------
    const int wave = t >> 6;                   // 0..7 -> col block wave*96
    const int lane = t & 63;
    const int quad = lane >> 4;
    const int l16 = lane & 15;

    const unsigned short* bcol[6];
    #pragma unroll
    for (int n = 0; n < 6; n++)
        bcol[n] = Wo + (size_t)(wave * 96 + n * 16 + l16) * E_DIM + quad * 8;

    f4v acc[4][6] = {};

    for (int k0 = 0; k0 < E_DIM; k0 += 32) {
        const int kc = (k0 >> 3) + quad;       // A col16 before swizzle
        s8v af[4], bf[6];
        #pragma unroll
        for (int m = 0; m < 4; m++) {
            const int r = m * 16 + l16;
            af[m] = *(const s8v*)(&Ams[((size_t)r * 96 + (kc ^ (r & 7))) * 8]);
        }
        #pragma unroll
        for (int n = 0; n < 6; n++)
            bf[n] = *(const s8v*)(bcol[n] + k0);
        #pragma unroll
        for (int m = 0; m < 4; m++)
            #pragma unroll
            for (int n = 0; n < 6; n++)
                acc[m][n] = __builtin_amdgcn_mfma_f32_16x16x32_bf16(af[m], bf[n], acc[m][n], 0, 0, 0);
    }

    #pragma unroll
    for (int m = 0; m < 4; m++) {
        const int gm_base = row0 + m * 16 + quad * 4;
        #pragma unroll
        for (int n = 0; n < 6; n++) {
            const int gn = wave * 96 + n * 16 + l16;
            const float bv = bias[gn];
            #pragma unroll
            for (int r = 0; r < 4; r++) {
                const int gm = gm_base + r;
                const size_t idx = (size_t)gm * E_DIM + gn;
                const float qv = query[idx];
                const float qln = (qv - qstats[gm * 2]) * qstats[gm * 2 + 1] * lnw[gn] + lnb[gn];
                out[idx] = qv + gamma[gn] * (qln + acc[m][n][r] + bv);
            }
        }
    }
}

// ---------------------------------------------------------------------------
extern "C" void kernel_launch(void* const* d_in, const int* in_sizes, int n_in,
                              void* d_out, int out_size, void* d_ws, size_t ws_size,
                              hipStream_t stream) {
    (void)in_sizes; (void)n_in; (void)out_size; (void)ws_size;

    const float* query  = (const float*)d_in[0];
    const float* refp   = (const float*)d_in[1];
    const float* feat   = (const float*)d_in[2];
    const float* ln_q_w = (const float*)d_in[5];
    const float* ln_q_b = (const float*)d_in[6];
    const float* ln_f_w = (const float*)d_in[7];
    const float* ln_f_b = (const float*)d_in[8];
    const float* W_val  = (const float*)d_in[9];
    const float* b_val  = (const float*)d_in[10];
    const float* W_off  = (const float*)d_in[11];
    const float* b_off  = (const float*)d_in[12];
    const float* W_attn = (const float*)d_in[13];
    const float* b_attn = (const float*)d_in[14];
    const float* W_out  = (const float*)d_in[15];
    const float* b_out  = (const float*)d_in[16];
    const float* gamma  = (const float*)d_in[17];
    float* out = (float*)d_out;

    const int MQ = BB * NQS;   // 16384
    const int MV = BB * NVS;   // 36864

    // Workspace layout (bytes)
    char* ws = (char*)d_ws;
    float*          q_stats = (float*)(ws + 0);                   //     131,072
    unsigned short* qbf     = (unsigned short*)(ws + 131072);     //  25,165,824
    unsigned short* fbf     = (unsigned short*)(ws + 25296896);   //  56,623,104
    unsigned short* val_bf  = (unsigned short*)(ws + 81920000);   //  56,623,104 (B,H,S,D)
    float*          offattn = (float*)(ws + 163708928);           //   8,388,608
    unsigned short* Wv_t    = (unsigned short*)(ws + 172097536);  //   1,179,648
    unsigned short* Wo_t    = (unsigned short*)(ws + 173277184);  //   1,179,648
    unsigned short* Wqc_t   = (unsigned short*)(ws + 174456832);  //     196,608
    float*          bcat    = (float*)(ws + 174653440);           //         512

    // 1. prep: LN (query+feat) + both weight transposes + wqc concat
    prep_kernel<<<NLNB + NTRB + 384, 256, 0, stream>>>(
        query, feat, ln_q_w, ln_q_b, ln_f_w, ln_f_b, qbf, fbf, q_stats,
        W_val, W_out, Wv_t, Wo_t, W_off, W_attn, b_off, b_attn, Wqc_t, bcat);

    // 2. fat GEMM: value (256^2, 432 blocks) + offsets (128^2, 128 tail blocks)
    mfma_gemm256<<<NVALB + 128, 512, 0, stream>>>(
        fbf, Wv_t, b_val, val_bf, qbf, Wqc_t, bcat, offattn);

    // 3. fused msda + out-proj + final residual (256 blocks, 1/CU, XCD-chunked)
    msda_oproj_kernel<<<MQ / OROWS, 512, 0, stream>>>(
        val_bf, offattn, refp, Wo_t, b_out, query, q_stats, ln_q_w, ln_q_b,
        gamma, out);
}